// Round 1
// baseline (289.851 us; speedup 1.0000x reference)
//
#include <hip/hip_runtime.h>

#define BS 24
#define CREP 16
#define HH 320
#define WW 320
#define HW (HH * WW)            // 102400
#define TOTAL (BS * HW)         // 2457600
#define NMP 4
#define NSEG 16                 // 4 classes * 4 micro-protos
#define NELEM 272               // 256 channel-sums + 16 counts
#define MOM 0.99f

// ---------------------------------------------------------------------------
// Kernel 0: detect whether `cond` (jnp.bool_) was uploaded as 1-byte bools or
// as int32. If byte-packed, interpreting the first 256 words as u32 yields
// values > 1 with overwhelming probability (each word needs its top 3 random
// 0/1 bytes all zero to stay <=1: p = 1/8 per word, (1/8)^256 overall miss).
// ---------------------------------------------------------------------------
__global__ void detect_cond_kernel(const unsigned int* __restrict__ cond_u32,
                                   int* __restrict__ flag) {
    bool big = false;
    for (int i = threadIdx.x; i < 256; i += 64)
        big |= (cond_u32[i] > 1u);
    unsigned long long b = __ballot(big);
    if (threadIdx.x == 0) flag[0] = (b != 0ull) ? 1 : 0;   // 1 => byte layout
}

// ---------------------------------------------------------------------------
// Kernel 1: grid-stride accumulation into per-block LDS, then one transposed
// partial-write per block (no global atomics).
// ---------------------------------------------------------------------------
__global__ __launch_bounds__(256) void accum_kernel(
    const float* __restrict__ rep,
    const int* __restrict__ pmi,
    const int* __restrict__ tgt,
    const int* __restrict__ smask,
    const unsigned char* __restrict__ cond_b,
    const int* __restrict__ flag,
    float* __restrict__ partials,
    int NB)
{
    // LDS: sums at [seg*17 + c] (pad 17 breaks bank aliasing), counts at 272+seg
    __shared__ float lds[288];
    for (int i = threadIdx.x; i < 288; i += 256) lds[i] = 0.0f;
    __syncthreads();

    const int byte_layout = flag[0];
    const int* cond_i = (const int*)cond_b;

    const int stride = gridDim.x * 256;
    for (int n = blockIdx.x * 256 + threadIdx.x; n < TOTAL; n += stride) {
        const int t  = tgt[n];
        const int hw = n % HW;
        bool v = (t != 0) && (smask[hw] == 1);
        if (v) {
            const int cv = byte_layout ? (int)cond_b[n] : cond_i[n];
            v = (cv != 0);
        }
        if (v) {
            const int b    = n / HW;
            const int pidx = pmi[n * 4 + t];
            const int seg  = t * NMP + pidx;
            const float* r = rep + (size_t)b * CREP * HW + hw;
            atomicAdd(&lds[272 + seg], 1.0f);
#pragma unroll
            for (int c = 0; c < CREP; ++c)
                atomicAdd(&lds[seg * 17 + c], r[c * HW]);
        }
    }
    __syncthreads();

    // transposed partials: partials[elem * NB + block] -> coalesced reduce
    for (int e = threadIdx.x; e < NELEM; e += 256) {
        float val = (e < 256) ? lds[(e >> 4) * 17 + (e & 15)]
                              : lds[272 + (e - 256)];
        partials[(size_t)e * NB + blockIdx.x] = val;
    }
}

// ---------------------------------------------------------------------------
// Kernel 2: 256 waves, one per (seg, channel). Each wave reduces its sum and
// (redundantly) its segment count over NB blocks, then lane 0 writes the EMA.
// ---------------------------------------------------------------------------
__global__ __launch_bounds__(256) void reduce_kernel(
    const float* __restrict__ partials,
    const float* __restrict__ protos,
    float* __restrict__ out,
    int NB)
{
    const int w    = (blockIdx.x * 256 + threadIdx.x) >> 6;  // 0..255
    const int lane = threadIdx.x & 63;
    const int seg  = w >> 4;

    float s = 0.0f, cnt = 0.0f;
    for (int b = lane; b < NB; b += 64) {
        s   += partials[(size_t)w * NB + b];
        cnt += partials[(size_t)(256 + seg) * NB + b];
    }
#pragma unroll
    for (int off = 32; off > 0; off >>= 1) {
        s   += __shfl_xor(s, off, 64);
        cnt += __shfl_xor(cnt, off, 64);
    }
    if (lane == 0) {
        const float mean = s / fmaxf(cnt, 1.0f);
        out[w] = (cnt > 0.0f) ? (MOM * protos[w] + (1.0f - MOM) * mean)
                              : protos[w];
    }
}

extern "C" void kernel_launch(void* const* d_in, const int* in_sizes, int n_in,
                              void* d_out, int out_size, void* d_ws, size_t ws_size,
                              hipStream_t stream) {
    const float*         rep    = (const float*)d_in[0];
    const int*           pmi    = (const int*)d_in[1];
    const int*           tgt    = (const int*)d_in[2];
    const int*           smask  = (const int*)d_in[3];
    const unsigned char* cond   = (const unsigned char*)d_in[4];
    const float*         protos = (const float*)d_in[5];
    float*               out    = (float*)d_out;

    // workspace layout: [NELEM * NB floats partials][1 int flag]
    int NB = (int)((ws_size / sizeof(float) - 16) / NELEM);
    if (NB > 2048) NB = 2048;
    if (NB < 1)    NB = 1;
    float* partials = (float*)d_ws;
    int*   flag     = (int*)d_ws + (size_t)NELEM * NB;

    detect_cond_kernel<<<1, 64, 0, stream>>>((const unsigned int*)cond, flag);
    accum_kernel<<<NB, 256, 0, stream>>>(rep, pmi, tgt, smask, cond, flag,
                                         partials, NB);
    reduce_kernel<<<64, 256, 0, stream>>>(partials, protos, out, NB);
}

// Round 2
// 282.420 us; speedup vs baseline: 1.0263x; 1.0263x over previous
//
#include <hip/hip_runtime.h>

#define BS 24
#define CREP 16
#define HH 320
#define WW 320
#define HW (HH * WW)            // 102400
#define TOTAL (BS * HW)         // 2457600
#define NMP 4
#define NSEG 16                 // 4 classes * 4 micro-protos
#define NELEM 272               // 256 channel-sums + 16 counts
#define MOM 0.99f

#define TILE 2048               // pixels per block (within one batch image)
#define TPB (TILE / 4 / 256)    // int4/float4 groups per thread = 2
#define NTILES (HW / TILE)      // 50
#define NBLK (BS * NTILES)      // 1200

// ---------------------------------------------------------------------------
// Kernel 0: detect whether `cond` (jnp.bool_) arrived as 1-byte bools or
// int32. Byte-packed random 0/1 bools make a u32 word >1 with p=7/8 per word;
// all 256 words <=1 has probability 8^-256 — effectively impossible.
// ---------------------------------------------------------------------------
__global__ void detect_cond_kernel(const unsigned int* __restrict__ cond_u32,
                                   int* __restrict__ flag) {
    bool big = false;
    for (int i = threadIdx.x; i < 256; i += 64)
        big |= (cond_u32[i] > 1u);
    unsigned long long b = __ballot(big);
    if (threadIdx.x == 0) flag[0] = (b != 0ull) ? 1 : 0;   // 1 => byte layout
}

// ---------------------------------------------------------------------------
// Kernel 1: per-block tile. Phase 1: compute seg byte per pixel (vectorized
// metadata loads). Phase 2: stream rep as float4, exec-masked LDS atomics.
// ---------------------------------------------------------------------------
__global__ __launch_bounds__(256) void accum_kernel(
    const float* __restrict__ rep,
    const int* __restrict__ pmi,
    const int* __restrict__ tgt,
    const int* __restrict__ smask,
    const unsigned char* __restrict__ cond_b,
    const int* __restrict__ flag,
    float* __restrict__ partials)
{
    __shared__ unsigned int segp[TILE / 4];   // packed seg bytes, 4 px/word
    __shared__ float acc[NSEG * 17];          // [seg][c], pad 17
    __shared__ float cnt[NSEG];

    for (int i = threadIdx.x; i < NSEG * 17; i += 256) acc[i] = 0.0f;
    if (threadIdx.x < NSEG) cnt[threadIdx.x] = 0.0f;
    __syncthreads();

    const int b    = blockIdx.x / NTILES;
    const int tile = blockIdx.x % NTILES;
    const int hw0  = tile * TILE;
    const int p0   = b * HW + hw0;            // global pixel base
    const int byte_layout = flag[0];

    const int4* tgt4  = (const int4*)(tgt + p0);
    const int4* sm4   = (const int4*)(smask + hw0);
    const int4* cond4 = (const int4*)((const int*)cond_b + p0);
    const unsigned int* condb4 = (const unsigned int*)(cond_b + p0);

    // ---- phase 1: seg bytes + counts --------------------------------------
#pragma unroll
    for (int j = 0; j < TPB; ++j) {
        const int g  = threadIdx.x + j * 256;     // int4 group within tile
        const int4 t4 = tgt4[g];
        const int4 s4 = sm4[g];
        int cc[4];
        if (byte_layout) {
            const unsigned int cb = condb4[g];
            cc[0] = cb & 0xff; cc[1] = (cb >> 8) & 0xff;
            cc[2] = (cb >> 16) & 0xff; cc[3] = (cb >> 24) & 0xff;
        } else {
            const int4 ci = cond4[g];
            cc[0] = ci.x; cc[1] = ci.y; cc[2] = ci.z; cc[3] = ci.w;
        }
        const int tt[4] = {t4.x, t4.y, t4.z, t4.w};
        const int ss[4] = {s4.x, s4.y, s4.z, s4.w};
        unsigned int packed = 0;
#pragma unroll
        for (int k = 0; k < 4; ++k) {
            int seg = 255;
            if (tt[k] != 0 && ss[k] == 1 && cc[k] != 0) {
                const int pidx = pmi[(p0 + g * 4 + k) * 4 + tt[k]];
                seg = tt[k] * NMP + pidx;
                atomicAdd(&cnt[seg], 1.0f);
            }
            packed |= (unsigned int)(seg & 0xff) << (8 * k);
        }
        segp[g] = packed;
    }
    __syncthreads();

    // hoist seg decode: per (j,k) LDS row base (seg*17), -1 if invalid
    int base[TPB][4];
#pragma unroll
    for (int j = 0; j < TPB; ++j) {
        const unsigned int sp = segp[threadIdx.x + j * 256];
#pragma unroll
        for (int k = 0; k < 4; ++k) {
            const int seg = (sp >> (8 * k)) & 0xff;
            base[j][k] = (seg == 255) ? -1 : seg * 17;
        }
    }

    // ---- phase 2: stream rep, LDS-atomic accumulate -----------------------
    const float4* r4 = (const float4*)(rep + (size_t)b * CREP * HW + hw0);
#pragma unroll 1
    for (int c = 0; c < CREP; c += 2) {
        float4 va[2][TPB];
#pragma unroll
        for (int cc2 = 0; cc2 < 2; ++cc2)
#pragma unroll
            for (int j = 0; j < TPB; ++j)
                va[cc2][j] = r4[(size_t)(c + cc2) * (HW / 4) + threadIdx.x + j * 256];
#pragma unroll
        for (int cc2 = 0; cc2 < 2; ++cc2)
#pragma unroll
            for (int j = 0; j < TPB; ++j) {
                const float vv[4] = {va[cc2][j].x, va[cc2][j].y,
                                     va[cc2][j].z, va[cc2][j].w};
#pragma unroll
                for (int k = 0; k < 4; ++k)
                    if (base[j][k] >= 0)
                        atomicAdd(&acc[base[j][k] + c + cc2], vv[k]);
            }
    }
    __syncthreads();

    // ---- write transposed partials ----------------------------------------
    for (int e = threadIdx.x; e < NELEM; e += 256) {
        const float val = (e < 256) ? acc[(e >> 4) * 17 + (e & 15)]
                                    : cnt[e - 256];
        partials[(size_t)e * NBLK + blockIdx.x] = val;
    }
}

// ---------------------------------------------------------------------------
// Kernel 2: 256 waves, one per (seg, channel); reduce partials + EMA.
// ---------------------------------------------------------------------------
__global__ __launch_bounds__(256) void reduce_kernel(
    const float* __restrict__ partials,
    const float* __restrict__ protos,
    float* __restrict__ out)
{
    const int w    = (blockIdx.x * 256 + threadIdx.x) >> 6;  // 0..255
    const int lane = threadIdx.x & 63;
    const int seg  = w >> 4;

    float s = 0.0f, cntv = 0.0f;
    for (int b = lane; b < NBLK; b += 64) {
        s    += partials[(size_t)w * NBLK + b];
        cntv += partials[(size_t)(256 + seg) * NBLK + b];
    }
#pragma unroll
    for (int off = 32; off > 0; off >>= 1) {
        s    += __shfl_xor(s, off, 64);
        cntv += __shfl_xor(cntv, off, 64);
    }
    if (lane == 0) {
        const float mean = s / fmaxf(cntv, 1.0f);
        out[w] = (cntv > 0.0f) ? (MOM * protos[w] + (1.0f - MOM) * mean)
                               : protos[w];
    }
}

extern "C" void kernel_launch(void* const* d_in, const int* in_sizes, int n_in,
                              void* d_out, int out_size, void* d_ws, size_t ws_size,
                              hipStream_t stream) {
    const float*         rep    = (const float*)d_in[0];
    const int*           pmi    = (const int*)d_in[1];
    const int*           tgt    = (const int*)d_in[2];
    const int*           smask  = (const int*)d_in[3];
    const unsigned char* cond   = (const unsigned char*)d_in[4];
    const float*         protos = (const float*)d_in[5];
    float*               out    = (float*)d_out;

    float* partials = (float*)d_ws;
    int*   flag     = (int*)d_ws + (size_t)NELEM * NBLK;

    detect_cond_kernel<<<1, 64, 0, stream>>>((const unsigned int*)cond, flag);
    accum_kernel<<<NBLK, 256, 0, stream>>>(rep, pmi, tgt, smask, cond, flag,
                                           partials);
    reduce_kernel<<<64, 256, 0, stream>>>(partials, protos, out);
}